// Round 1
// 392.763 us; speedup vs baseline: 1.1725x; 1.1725x over previous
//
#include <hip/hip_runtime.h>

#define T_SEQ 2000
#define N_UTT 64
#define DQ 256
#define NTOK 10
#define NH 8
#define DS 32
#define NC 80          // logit columns = NH * NTOK
#define LGS 84         // LDS row stride for logits

typedef float f32x4 __attribute__((ext_vector_type(4)));
typedef short s16x8 __attribute__((ext_vector_type(8)));

__device__ __forceinline__ unsigned short f2bf(float f){
    unsigned int u = __float_as_uint(f);
    u += 0x7FFFu + ((u >> 16) & 1u);     // round-to-nearest-even
    return (unsigned short)(u >> 16);
}
__device__ __forceinline__ float bf2f(unsigned short h){
    return __uint_as_float(((unsigned int)h) << 16);
}

// prep 1: khd/vhd[tok][u] = (tanh(embed) @ Wk^T / Wv^T), fp32
__global__ __launch_bounds__(256) void prep_kv(
    const float* __restrict__ embed, const float* __restrict__ Wk,
    const float* __restrict__ Wv, float* __restrict__ khd, float* __restrict__ vhd)
{
    __shared__ float th[NTOK*DS];
    const int u = threadIdx.x;
    for (int i = u; i < NTOK*DS; i += 256) th[i] = tanhf(embed[i]);
    __syncthreads();
    for (int tok = 0; tok < NTOK; ++tok){
        float ka = 0.f, va = 0.f;
        #pragma unroll
        for (int d = 0; d < DS; ++d){
            const float kd = th[tok*DS + d];
            ka += kd * Wk[u*DS + d];
            va += kd * Wv[u*DS + d];
        }
        khd[tok*DQ + u] = ka;
        vhd[tok*DQ + u] = va;
    }
}

// prep 2: fold k into Wq:  Wl[c= h*10+tok][q] = scale * sum_d Wq[h*32+d][q]*khd[tok][h*32+d]
// stored split as bf16 hi/lo for 3-product MFMA (~fp32 logits).
__global__ __launch_bounds__(256) void prep_wl(
    const float* __restrict__ Wq, const float* __restrict__ khd,
    unsigned short* __restrict__ WlH, unsigned short* __restrict__ WlL)
{
    const int c = blockIdx.x;            // 0..79
    const int q = threadIdx.x;           // 0..255
    const int h = c / NTOK, tok = c - h*NTOK;
    float s = 0.f;
    #pragma unroll
    for (int d = 0; d < DS; ++d)
        s += Wq[(size_t)(h*DS + d)*DQ + q] * khd[tok*DQ + h*DS + d];
    s *= 0.17677669529663687f;           // 1/sqrt(32) folded in
    const unsigned short hi = f2bf(s);
    const unsigned short lo = f2bf(s - bf2f(hi));
    WlH[c*DQ + q] = hi;
    WlL[c*DQ + q] = lo;
}

// main: one wave (64 threads) per block, 32 rows per wave, no barriers.
__global__ __launch_bounds__(64, 4) void main_kernel(
    const float* __restrict__ inputs, const int* __restrict__ pidx,
    const float* __restrict__ pos_table, const unsigned short* __restrict__ WlH,
    const unsigned short* __restrict__ WlL, const float* __restrict__ vhd,
    float* __restrict__ outp, float* __restrict__ scores)
{
    __shared__ float lg[2][16][LGS];     // 10752 B, wave-private
    const int lane = threadIdx.x;
    const int lrow = lane & 15;          // A: m index / B: n index
    const int quad = lane >> 4;          // A,B: k = quad*8+j ; D: row = quad*4+reg
    const int m0   = blockIdx.x * 32;    // flat row tile (128000 rows total)

    const int rowA = m0 + lrow;          // mt = 0
    const int rowB = rowA + 16;          // mt = 1
    const int idxA = pidx[rowA];
    const int idxB = pidx[rowB];

    f32x4 acc[2][5] = {};                // 2 row-subtiles x 5 col-tiles (80 logits)

    for (int kt = 0; kt < 8; ++kt){
        const int kq = kt*32 + quad*8;
        s16x8 ah[2], al[2];
        #pragma unroll
        for (int mt = 0; mt < 2; ++mt){
            const float* xp = inputs    + (size_t)(mt ? rowB : rowA)*DQ + kq;
            const float* pp = pos_table + (size_t)(mt ? idxB : idxA)*DQ + kq;
            f32x4 x0 = *(const f32x4*)xp;
            f32x4 x1 = *(const f32x4*)(xp + 4);
            x0 += *(const f32x4*)pp;
            x1 += *(const f32x4*)(pp + 4);
            s16x8 h8, l8;
            #pragma unroll
            for (int j = 0; j < 4; ++j){
                const unsigned short hv = f2bf(x0[j]);
                h8[j]   = (short)hv;
                l8[j]   = (short)f2bf(x0[j] - bf2f(hv));
                const unsigned short hw = f2bf(x1[j]);
                h8[4+j] = (short)hw;
                l8[4+j] = (short)f2bf(x1[j] - bf2f(hw));
            }
            ah[mt] = h8; al[mt] = l8;
        }
        #pragma unroll
        for (int ct = 0; ct < 5; ++ct){
            // B[k][n] = Wl[n][k]; lane reads 8 contiguous k at row n=ct*16+lrow (16B, L1/L2-hot)
            const s16x8 bh = *(const s16x8*)(WlH + (ct*16 + lrow)*DQ + kq);
            const s16x8 bl = *(const s16x8*)(WlL + (ct*16 + lrow)*DQ + kq);
            #pragma unroll
            for (int mt = 0; mt < 2; ++mt){
                acc[mt][ct] = __builtin_amdgcn_mfma_f32_16x16x32_bf16(al[mt], bh, acc[mt][ct], 0,0,0);
                acc[mt][ct] = __builtin_amdgcn_mfma_f32_16x16x32_bf16(ah[mt], bl, acc[mt][ct], 0,0,0);
                acc[mt][ct] = __builtin_amdgcn_mfma_f32_16x16x32_bf16(ah[mt], bh, acc[mt][ct], 0,0,0);
            }
        }
    }

    // D -> LDS transpose buffer (row = quad*4+reg, col = ct*16+lrow; verified layout)
    #pragma unroll
    for (int mt = 0; mt < 2; ++mt)
        #pragma unroll
        for (int ct = 0; ct < 5; ++ct)
            #pragma unroll
            for (int reg = 0; reg < 4; ++reg)
                lg[mt][quad*4 + reg][ct*16 + lrow] = acc[mt][ct][reg];

    // attention: lane -> (r = lrow, head = quad + 4*hh); both row-subtiles share vhd loads
    const int r = lrow;
    #pragma unroll
    for (int hh = 0; hh < 2; ++hh){
        const int h = quad + hh*4;
        float p[2][NTOK];
        #pragma unroll
        for (int mt = 0; mt < 2; ++mt){
            float lv[NTOK];
            #pragma unroll
            for (int k = 0; k < NTOK; ++k) lv[k] = lg[mt][r][h*NTOK + k];
            float mx = lv[0];
            #pragma unroll
            for (int k = 1; k < NTOK; ++k) mx = fmaxf(mx, lv[k]);
            float s = 0.f;
            #pragma unroll
            for (int k = 0; k < NTOK; ++k){ p[mt][k] = __expf(lv[k] - mx); s += p[mt][k]; }
            const float inv = 1.f / s;
            const int row = m0 + mt*16 + r;
            const int n = row / T_SEQ;
            const int t = row - n*T_SEQ;
            float* sp = scores + (size_t)(n*(NH*NTOK) + h*NTOK)*T_SEQ + t;
            #pragma unroll
            for (int k = 0; k < NTOK; ++k){
                p[mt][k] *= inv;
                sp[(size_t)k*T_SEQ] = p[mt][k];      // scores[n][h*10+k][t]
            }
        }
        float* o0 = outp + (size_t)(m0 + r)*DQ + h*DS;
        float* o1 = outp + (size_t)(m0 + 16 + r)*DQ + h*DS;
        #pragma unroll
        for (int db = 0; db < 8; ++db){
            f32x4 a0 = {}, a1 = {};
            #pragma unroll
            for (int k = 0; k < NTOK; ++k){
                const f32x4 vv = *(const f32x4*)(vhd + k*DQ + h*DS + db*4);  // L1-hot broadcast
                a0 += p[0][k] * vv;
                a1 += p[1][k] * vv;
            }
            *(f32x4*)(o0 + db*4) = a0;
            *(f32x4*)(o1 + db*4) = a1;
        }
    }
}

extern "C" void kernel_launch(void* const* d_in, const int* in_sizes, int n_in,
                              void* d_out, int out_size, void* d_ws, size_t ws_size,
                              hipStream_t stream)
{
    const float* inputs    = (const float*)d_in[0];
    const int*   pidx      = (const int*)d_in[1];   // integer input -> int32 per harness
    const float* embed     = (const float*)d_in[2];
    const float* Wq        = (const float*)d_in[3];
    const float* Wk        = (const float*)d_in[4];
    const float* Wv        = (const float*)d_in[5];
    const float* pos_table = (const float*)d_in[6];

    float* outp   = (float*)d_out;                          // [64*2000*256]
    float* scores = outp + (size_t)N_UTT*T_SEQ*DQ;          // [64*80*2000]

    float* khd = (float*)d_ws;                              // 10*256 f32
    float* vhd = khd + NTOK*DQ;                             // 10*256 f32
    unsigned short* WlH = (unsigned short*)(vhd + NTOK*DQ); // 80*256 bf16 hi
    unsigned short* WlL = WlH + NC*DQ;                      // 80*256 bf16 lo

    prep_kv<<<1, 256, 0, stream>>>(embed, Wk, Wv, khd, vhd);
    prep_wl<<<NC, 256, 0, stream>>>(Wq, khd, WlH, WlL);
    main_kernel<<<(N_UTT*T_SEQ)/32, 64, 0, stream>>>(inputs, pidx, pos_table,
                                                     WlH, WlL, vhd, outp, scores);
}